// Round 1
// baseline (220.501 us; speedup 1.0000x reference)
//
#include <hip/hip_runtime.h>

#define NB 4
#define NN 2048
#define KK 32
#define DD 64
#define R2C 0.64f

// ---------------- prep: combined layer-0 weights ----------------
// w0x[j][c] = Wf[j][c] - Wf[128+j][c]      (x part, goes into bases)
// w0k[j][c] = Wf[64+j][c] + Wf[128+j][c]   (neighbor part, main kernel)
__global__ __launch_bounds__(256) void prep_w_kernel(const float* __restrict__ Wf,
                                                     float* __restrict__ w0x,
                                                     float* __restrict__ w0k) {
    int t = blockIdx.x * 256 + threadIdx.x;
    if (t < 64 * 32) {
        float a = Wf[t];
        float bk = Wf[64 * 32 + t];
        float dd = Wf[128 * 32 + t];
        w0x[t] = a - dd;
        w0k[t] = bk + dd;
    }
}

// ---------------- ball query ----------------
// first K ascending indices m with d2 < r^2; pad with first hit.
// d2 computed exactly as reference: (sq[n]+sq[m]) - 2*dot, no FMA contraction.
__global__ __launch_bounds__(256) void ball_query_kernel(const float* __restrict__ pos,
                                                         int* __restrict__ idx) {
    __shared__ float sp[NN * 3];
    __shared__ float sq[NN];
    int bb = blockIdx.x >> 3;          // 8 blocks per batch
    int nbase = (blockIdx.x & 7) * 256;
    const float* pb = pos + bb * NN * 3;
    for (int i = threadIdx.x; i < NN * 3; i += 256) sp[i] = pb[i];
    __syncthreads();
    for (int i = threadIdx.x; i < NN; i += 256) {
        float px = sp[i * 3], py = sp[i * 3 + 1], pz = sp[i * 3 + 2];
        sq[i] = __fadd_rn(__fadd_rn(__fmul_rn(px, px), __fmul_rn(py, py)), __fmul_rn(pz, pz));
    }
    __syncthreads();

    int n = nbase + threadIdx.x;
    float qx = sp[n * 3], qy = sp[n * 3 + 1], qz = sp[n * 3 + 2];
    float sqn = sq[n];
    int* op = idx + (bb * NN + n) * KK;
    int cnt = 0;
    for (int m = 0; m < NN; ++m) {
        float mx = sp[m * 3], my = sp[m * 3 + 1], mz = sp[m * 3 + 2];
        float dot = __fadd_rn(__fadd_rn(__fmul_rn(qx, mx), __fmul_rn(qy, my)), __fmul_rn(qz, mz));
        float d2 = __fsub_rn(__fadd_rn(sqn, sq[m]), __fmul_rn(2.0f, dot));
        if (d2 < R2C) {
            op[cnt++] = m;
            if (cnt == KK) break;
        }
    }
    int first = op[0];  // self always within -> cnt >= 1
    for (; cnt < KK; ++cnt) op[cnt] = first;
}

// ---------------- per-query bases: 4x32 channels of x-only partial sums ----------------
// lane = query; weights wave-uniform -> SGPR; 8192 FMA per lane.
__global__ __launch_bounds__(64) void bases_kernel(const float* __restrict__ x,
                                                   const float* __restrict__ w0x,
                                                   const float* __restrict__ W1,
                                                   const float* __restrict__ W2,
                                                   const float* __restrict__ Wl,
                                                   const float* __restrict__ bf,
                                                   const float* __restrict__ b1,
                                                   const float* __restrict__ b2,
                                                   const float* __restrict__ bl,
                                                   float* __restrict__ bases) {
    int q = blockIdx.x * 64 + threadIdx.x;
    const float4* xr = (const float4*)(x + (size_t)q * DD);
    float a0[32], a1[32], a2[32], a3[32];
#pragma unroll
    for (int c = 0; c < 32; ++c) { a0[c] = bf[c]; a1[c] = b1[c]; a2[c] = b2[c]; a3[c] = bl[c]; }
    for (int j0 = 0; j0 < 16; ++j0) {
        float4 xv = xr[j0];
        float xs[4] = {xv.x, xv.y, xv.z, xv.w};
#pragma unroll
        for (int jj = 0; jj < 4; ++jj) {
            int j = j0 * 4 + jj;
            float v = xs[jj];
#pragma unroll
            for (int c = 0; c < 32; ++c) {
                a0[c] = fmaf(v, w0x[j * 32 + c], a0[c]);
                a1[c] = fmaf(v, W1[(32 + j) * 32 + c], a1[c]);
                a2[c] = fmaf(v, W2[(64 + j) * 32 + c], a2[c]);
                a3[c] = fmaf(v, Wl[(96 + j) * 32 + c], a3[c]);
            }
        }
    }
    float* bq = bases + (size_t)q * 128;
    float4* b4 = (float4*)bq;
#pragma unroll
    for (int c = 0; c < 8; ++c) b4[c]      = make_float4(a0[4*c], a0[4*c+1], a0[4*c+2], a0[4*c+3]);
#pragma unroll
    for (int c = 0; c < 8; ++c) b4[8 + c]  = make_float4(a1[4*c], a1[4*c+1], a1[4*c+2], a1[4*c+3]);
#pragma unroll
    for (int c = 0; c < 8; ++c) b4[16 + c] = make_float4(a2[4*c], a2[4*c+1], a2[4*c+2], a2[4*c+3]);
#pragma unroll
    for (int c = 0; c < 8; ++c) b4[24 + c] = make_float4(a3[4*c], a3[4*c+1], a3[4*c+2], a3[4*c+3]);
}

// ---------------- helpers ----------------
__device__ __forceinline__ void load32(const float* __restrict__ p, float* h) {
#pragma unroll
    for (int c = 0; c < 8; ++c) {
        float4 v = ((const float4*)p)[c];
        h[4 * c] = v.x; h[4 * c + 1] = v.y; h[4 * c + 2] = v.z; h[4 * c + 3] = v.w;
    }
}

__device__ __forceinline__ void relu32(float* h) {
#pragma unroll
    for (int c = 0; c < 32; ++c) h[c] = fmaxf(h[c], 0.0f);
}

// hacc[c] += hin[i] * W[i*32+c], weights wave-uniform -> s_load
__device__ __forceinline__ void mlp_block(const float* hin, const float* __restrict__ W, float* hacc) {
#pragma unroll
    for (int i = 0; i < 32; ++i) {
        float hv = hin[i];
#pragma unroll
        for (int c = 0; c < 32; ++c) hacc[c] = fmaf(hv, W[i * 32 + c], hacc[c]);
    }
}

__device__ __forceinline__ void st32(float* p, const float* h) {
#pragma unroll
    for (int c = 0; c < 8; ++c)
        ((float4*)p)[c] = make_float4(h[4 * c], h[4 * c + 1], h[4 * c + 2], h[4 * c + 3]);
}

// ---------------- main: per-(query,k) MLP + max over k ----------------
// wave = 2 queries x 32 k-lanes. All 32 channels per lane in registers.
__global__ __launch_bounds__(256, 2) void mlp_kernel(const float* __restrict__ x,
                                                     const int* __restrict__ idx,
                                                     const float* __restrict__ bases,
                                                     const float* __restrict__ w0k,
                                                     const float* __restrict__ W1,
                                                     const float* __restrict__ W2,
                                                     const float* __restrict__ Wl,
                                                     float* __restrict__ out) {
    int wave = blockIdx.x * 4 + (threadIdx.x >> 6);
    int lane = threadIdx.x & 63;
    int half = lane >> 5;
    int k = lane & 31;
    int q = wave * 2 + half;        // [0, 8192)
    int b = q >> 11;

    int nb = idx[q * KK + k];
    const float4* xr = (const float4*)(x + ((size_t)(b * NN + nb)) * DD);
    const float* bq = bases + (size_t)q * 128;

    // ---- layer 0: h0 = relu(base0 + sum_j xk[j] * w0k[j][c]) ----
    float h0[32];
    load32(bq, h0);
    for (int j0 = 0; j0 < 16; ++j0) {
        float4 xv = xr[j0];
        const float* wr = w0k + j0 * 4 * 32;
#pragma unroll
        for (int c = 0; c < 32; ++c) h0[c] = fmaf(xv.x, wr[c], h0[c]);
#pragma unroll
        for (int c = 0; c < 32; ++c) h0[c] = fmaf(xv.y, wr[32 + c], h0[c]);
#pragma unroll
        for (int c = 0; c < 32; ++c) h0[c] = fmaf(xv.z, wr[64 + c], h0[c]);
#pragma unroll
        for (int c = 0; c < 32; ++c) h0[c] = fmaf(xv.w, wr[96 + c], h0[c]);
    }
    relu32(h0);

    // ---- layer 1: h1 = relu(base1 + h0 @ W1[0:32]) ----
    float h1[32];
    load32(bq + 32, h1);
    mlp_block(h0, W1, h1);
    relu32(h1);

    // ---- layer 2: h2 = relu(base2 + h1 @ W2[0:32] + h0 @ W2[32:64]) ----
    float h2[32];
    load32(bq + 64, h2);
    mlp_block(h1, W2, h2);
    mlp_block(h0, W2 + 32 * 32, h2);
    relu32(h2);

    // ---- layer 3: h3 = base3 + h2 @ Wl[0:32] + h1 @ Wl[32:64] + h0 @ Wl[64:96] ----
    float h3[32];
    load32(bq + 96, h3);
    mlp_block(h2, Wl, h3);
    mlp_block(h1, Wl + 32 * 32, h3);
    mlp_block(h0, Wl + 64 * 32, h3);

    // ---- max over k: 5-step butterfly within each 32-lane half ----
#pragma unroll
    for (int m = 1; m < 32; m <<= 1) {
#pragma unroll
        for (int c = 0; c < 32; ++c) h0[c] = fmaxf(h0[c], __shfl_xor(h0[c], m, 32));
#pragma unroll
        for (int c = 0; c < 32; ++c) h1[c] = fmaxf(h1[c], __shfl_xor(h1[c], m, 32));
#pragma unroll
        for (int c = 0; c < 32; ++c) h2[c] = fmaxf(h2[c], __shfl_xor(h2[c], m, 32));
#pragma unroll
        for (int c = 0; c < 32; ++c) h3[c] = fmaxf(h3[c], __shfl_xor(h3[c], m, 32));
    }

    // ---- store: out row = [h3, h2, h1, h0, x] ----
    float* orow = out + (size_t)q * 192;
    if (k == 0) {
        st32(orow, h3);
        st32(orow + 32, h2);
        st32(orow + 64, h1);
        st32(orow + 96, h0);
    }
    const float* xq = x + (size_t)q * DD;
    orow[128 + k] = xq[k];
    orow[160 + k] = xq[32 + k];
}

extern "C" void kernel_launch(void* const* d_in, const int* in_sizes, int n_in,
                              void* d_out, int out_size, void* d_ws, size_t ws_size,
                              hipStream_t stream) {
    const float* x   = (const float*)d_in[0];
    const float* pos = (const float*)d_in[1];
    const float* Wf  = (const float*)d_in[2];
    const float* bf  = (const float*)d_in[3];
    const float* W1  = (const float*)d_in[4];
    const float* b1  = (const float*)d_in[5];
    const float* W2  = (const float*)d_in[6];
    const float* b2  = (const float*)d_in[7];
    const float* Wl  = (const float*)d_in[8];
    const float* bl  = (const float*)d_in[9];
    float* out = (float*)d_out;

    char* ws = (char*)d_ws;
    int*   idx   = (int*)ws;                              // 4*2048*32*4 = 1 MB
    float* bases = (float*)(ws + (1u << 20));             // 8192*128*4  = 4 MB
    float* w0x   = (float*)(ws + 5u * (1u << 20));        // 8 KB
    float* w0k   = (float*)(ws + 5u * (1u << 20) + 8192); // 8 KB

    hipLaunchKernelGGL(prep_w_kernel, dim3(8), dim3(256), 0, stream, Wf, w0x, w0k);
    hipLaunchKernelGGL(ball_query_kernel, dim3(32), dim3(256), 0, stream, pos, idx);
    hipLaunchKernelGGL(bases_kernel, dim3(128), dim3(64), 0, stream,
                       x, w0x, W1, W2, Wl, bf, b1, b2, bl, bases);
    hipLaunchKernelGGL(mlp_kernel, dim3(1024), dim3(256), 0, stream,
                       x, idx, bases, w0k, W1, W2, Wl, out);
}